// Round 3
// baseline (2413.746 us; speedup 1.0000x reference)
//
#include <hip/hip_runtime.h>
#include <math.h>

#define NPTS 2048
#define BATCH 8
#define KNB 10

static __device__ __forceinline__ float lrelu(float x, float s){ return x >= 0.f ? x : s*x; }
static __device__ __forceinline__ double lrelu_d(double x, double s){ return x >= 0.0 ? x : s*x; }

// ---------------------------------------------------------------------------
// FAST conv1d as GEMM (FMA allowed): out[b,o,n] = act(sum_c W[o*ws+w0+c]*in[b,c,n] + bias[o] + addBO[b,o])
// ---------------------------------------------------------------------------
__global__ __launch_bounds__(256) void conv_gemm(
    const float* __restrict__ in, const float* __restrict__ W, int wstride, int wcol0,
    const float* __restrict__ bias, const float* __restrict__ addBO,
    float* __restrict__ out, int C, int M, int act, float neg)
{
  __shared__ float As[16][68];
  __shared__ float Bs[16][68];
  const int b = blockIdx.z;
  const int m0 = blockIdx.y*64, n0 = blockIdx.x*64;
  const int t = threadIdx.x;
  const int tm = t>>4, tn = t&15;
  float acc[4][4] = {};
  for (int k0 = 0; k0 < C; k0 += 16){
    #pragma unroll
    for (int i=0;i<4;i++){
      const int ii = t + i*256;
      const int k = ii&15, m = ii>>4;
      const int gm = m0+m, gk = k0+k;
      As[k][m] = (gm<M && gk<C) ? W[(size_t)gm*wstride + wcol0 + gk] : 0.f;
    }
    #pragma unroll
    for (int i=0;i<4;i++){
      const int ii = t + i*256;
      const int n = ii&63, k = ii>>6;
      const int gk = k0+k;
      Bs[k][n] = (gk<C) ? in[((size_t)b*C+gk)*NPTS + n0+n] : 0.f;
    }
    __syncthreads();
    #pragma unroll
    for (int k=0;k<16;k++){
      const float a0=As[k][tm*4+0], a1=As[k][tm*4+1], a2=As[k][tm*4+2], a3=As[k][tm*4+3];
      const float b0=Bs[k][tn*4+0], b1=Bs[k][tn*4+1], b2=Bs[k][tn*4+2], b3=Bs[k][tn*4+3];
      acc[0][0]+=a0*b0; acc[0][1]+=a0*b1; acc[0][2]+=a0*b2; acc[0][3]+=a0*b3;
      acc[1][0]+=a1*b0; acc[1][1]+=a1*b1; acc[1][2]+=a1*b2; acc[1][3]+=a1*b3;
      acc[2][0]+=a2*b0; acc[2][1]+=a2*b1; acc[2][2]+=a2*b2; acc[2][3]+=a2*b3;
      acc[3][0]+=a3*b0; acc[3][1]+=a3*b1; acc[3][2]+=a3*b2; acc[3][3]+=a3*b3;
    }
    __syncthreads();
  }
  #pragma unroll
  for (int i=0;i<4;i++){
    const int gm = m0 + tm*4 + i;
    if (gm < M){
      const float bv = bias ? bias[gm] : 0.f;
      const float av = addBO ? addBO[b*M+gm] : 0.f;
      #pragma unroll
      for (int j=0;j<4;j++){
        float v = acc[i][j] + bv + av;
        if (act) v = lrelu(v, neg);
        out[((size_t)b*M+gm)*NPTS + n0 + tn*4 + j] = v;
      }
    }
  }
}

// ---------------------------------------------------------------------------
// EXACT conv1d GEMM: bit-matches numpy einsum 'bcn,oc->bon' (+bias, opt lrelu):
// single f32 accumulator, ascending c, no FMA contraction.
// ---------------------------------------------------------------------------
__global__ __launch_bounds__(256) void conv_gemm_exact(
    const float* __restrict__ in, const float* __restrict__ W, int wstride, int wcol0,
    const float* __restrict__ bias,
    float* __restrict__ out, int C, int M, int act, float neg)
{
  __shared__ float As[16][68];
  __shared__ float Bs[16][68];
  const int b = blockIdx.z;
  const int m0 = blockIdx.y*64, n0 = blockIdx.x*64;
  const int t = threadIdx.x;
  const int tm = t>>4, tn = t&15;
  float acc[4][4] = {};
  for (int k0 = 0; k0 < C; k0 += 16){
    #pragma unroll
    for (int i=0;i<4;i++){
      const int ii = t + i*256;
      const int k = ii&15, m = ii>>4;
      const int gm = m0+m, gk = k0+k;
      As[k][m] = (gm<M && gk<C) ? W[(size_t)gm*wstride + wcol0 + gk] : 0.f;
    }
    #pragma unroll
    for (int i=0;i<4;i++){
      const int ii = t + i*256;
      const int n = ii&63, k = ii>>6;
      const int gk = k0+k;
      Bs[k][n] = (gk<C) ? in[((size_t)b*C+gk)*NPTS + n0+n] : 0.f;
    }
    __syncthreads();
    #pragma unroll
    for (int k=0;k<16;k++){    // ascending k total order; no FMA
      #pragma unroll
      for (int i=0;i<4;i++){
        const float a = As[k][tm*4+i];
        #pragma unroll
        for (int j=0;j<4;j++){
          acc[i][j] = __fadd_rn(acc[i][j], __fmul_rn(a, Bs[k][tn*4+j]));
        }
      }
    }
    __syncthreads();
  }
  #pragma unroll
  for (int i=0;i<4;i++){
    const int gm = m0 + tm*4 + i;
    if (gm < M){
      const float bv = bias ? bias[gm] : 0.f;
      #pragma unroll
      for (int j=0;j<4;j++){
        float v = __fadd_rn(acc[i][j], bv);
        if (act) v = (v >= 0.f) ? v : __fmul_rn(neg, v);
        out[((size_t)b*M+gm)*NPTS + n0 + tn*4 + j] = v;
      }
    }
  }
}

// ---------------------------------------------------------------------------
// Head layer 1 (EXACT): C=131 gathered from x (B,N,3), z (B,N,128); lrelu 0.01
// ---------------------------------------------------------------------------
__global__ __launch_bounds__(256) void head1_exact(
    const float* __restrict__ x, const float* __restrict__ z,
    const float* __restrict__ W, const float* __restrict__ bias,
    float* __restrict__ outh)
{
  __shared__ float As[16][68];
  __shared__ float Bs[16][68];
  const int b = blockIdx.z;
  const int m0 = blockIdx.y*64, n0 = blockIdx.x*64;
  const int t = threadIdx.x;
  const int tm = t>>4, tn = t&15;
  float acc[4][4] = {};
  for (int k0 = 0; k0 < 144; k0 += 16){
    #pragma unroll
    for (int i=0;i<4;i++){
      const int ii = t + i*256;
      const int k = ii&15, m = ii>>4;
      const int gk = k0+k;
      As[k][m] = (gk<131) ? W[(size_t)(m0+m)*131 + gk] : 0.f;
    }
    #pragma unroll
    for (int i=0;i<4;i++){
      const int ii = t + i*256;
      const int k = ii&15, nn = ii>>4;
      const int gk = k0+k, gn = n0+nn;
      float v = 0.f;
      if (gk < 3)        v = x[((size_t)b*NPTS+gn)*3   + gk];
      else if (gk < 131) v = z[((size_t)b*NPTS+gn)*128 + (gk-3)];
      Bs[k][nn] = v;
    }
    __syncthreads();
    #pragma unroll
    for (int k=0;k<16;k++){
      #pragma unroll
      for (int i=0;i<4;i++){
        const float a = As[k][tm*4+i];
        #pragma unroll
        for (int j=0;j<4;j++){
          acc[i][j] = __fadd_rn(acc[i][j], __fmul_rn(a, Bs[k][tn*4+j]));
        }
      }
    }
    __syncthreads();
  }
  #pragma unroll
  for (int i=0;i<4;i++){
    const int gm = m0 + tm*4 + i;
    #pragma unroll
    for (int j=0;j<4;j++){
      float v = __fadd_rn(acc[i][j], bias[gm]);
      v = (v >= 0.f) ? v : __fmul_rn(0.01f, v);
      outh[((size_t)b*128+gm)*NPTS + n0 + tn*4 + j] = v;
    }
  }
}

// ---------------------------------------------------------------------------
// Block-1 kNN: f32 np-exact. norms: ((x0^2+x1^2)+x2^2), no FMA.
// ---------------------------------------------------------------------------
__global__ __launch_bounds__(256) void norms3_f32(const float* __restrict__ Xn, float* __restrict__ XN)
{
  const int q = blockIdx.x*256 + threadIdx.x;
  const float* p = Xn + (size_t)q*3;
  float s = __fmul_rn(p[0],p[0]);
  s = __fadd_rn(s, __fmul_rn(p[1],p[1]));
  s = __fadd_rn(s, __fmul_rn(p[2],p[2]));
  XN[q] = s;
}

// dist = ((-2*dot) + qn) + xn, all f32, no FMA; stable (dist, idx) top-11.
// Stores dists as double (exact f32 cast) so one merge kernel serves both blocks.
__global__ __launch_bounds__(256) void knn_part3(
    const float* __restrict__ Xn, const float* __restrict__ XN,
    double* __restrict__ topd, int* __restrict__ topi)
{
  const int t = threadIdx.x;
  const int qloc = t & 31, part = t >> 5;
  const int q = blockIdx.x*32 + qloc;
  const int b = q >> 11, n = q & (NPTS-1);
  const float* xb = Xn + (size_t)b*NPTS*3;
  const float qx = xb[(size_t)n*3+0], qy = xb[(size_t)n*3+1], qz = xb[(size_t)n*3+2];
  const float qn = XN[q];
  float td[11]; int ti[11];
  #pragma unroll
  for (int r=0;r<11;r++){ td[r] = 3.4e38f; ti[r] = 0x7fffffff; }
  const int m0 = part*(NPTS/8);
  for (int mm=0; mm<NPTS/8; mm++){
    const int m = m0 + mm;
    float dot = __fmul_rn(qx, xb[(size_t)m*3+0]);
    dot = __fadd_rn(dot, __fmul_rn(qy, xb[(size_t)m*3+1]));
    dot = __fadd_rn(dot, __fmul_rn(qz, xb[(size_t)m*3+2]));
    float dist = __fmul_rn(-2.f, dot);
    dist = __fadd_rn(dist, qn);
    dist = __fadd_rn(dist, XN[b*NPTS + m]);
    if (dist < td[10]){
      td[10] = dist; ti[10] = m;
      #pragma unroll
      for (int p=10;p>0;p--){
        if (td[p] < td[p-1]){
          float tf=td[p]; td[p]=td[p-1]; td[p-1]=tf;
          int   tt=ti[p]; ti[p]=ti[p-1]; ti[p-1]=tt;
        }
      }
    }
  }
  const size_t base = ((size_t)q*8 + part)*11;
  #pragma unroll
  for (int r=0;r<11;r++){ topd[base+r] = (double)td[r]; topi[base+r] = ti[r]; }
}

// ---------------------------------------------------------------------------
// Block-2 kNN: f64 on f64 x1 (matches np's f64-promoted x1 path).
// ---------------------------------------------------------------------------
__global__ __launch_bounds__(256) void norms64d(const double* __restrict__ Xn, double* __restrict__ XN)
{
  const int q = blockIdx.x*256 + threadIdx.x;
  const double* p = Xn + (size_t)q*64;
  double s = 0.0;
  #pragma unroll
  for (int d=0; d<64; d++) s += p[d]*p[d];
  XN[q] = s;
}

__global__ __launch_bounds__(256) void knn_part64d(
    const double* __restrict__ Xn, const double* __restrict__ XN,
    double* __restrict__ topd, int* __restrict__ topi)
{
  const int t = threadIdx.x;
  const int qloc = t & 31, part = t >> 5;
  const int q = blockIdx.x*32 + qloc;
  const int b = q >> 11, n = q & (NPTS-1);
  const double* xb = Xn + (size_t)b*NPTS*64;
  double qv[64];
  {
    const double2* p2 = reinterpret_cast<const double2*>(xb + (size_t)n*64);
    #pragma unroll
    for (int d2=0; d2<32; d2++){ double2 v = p2[d2]; qv[d2*2]=v.x; qv[d2*2+1]=v.y; }
  }
  const double qn = XN[q];
  double td[11]; int ti[11];
  #pragma unroll
  for (int r=0;r<11;r++){ td[r] = 1.0e308; ti[r] = 0x7fffffff; }
  const int m0 = part*(NPTS/8);
  for (int mm=0; mm<NPTS/8; mm++){
    const int m = m0 + mm;
    const double2* c2 = reinterpret_cast<const double2*>(xb + (size_t)m*64);
    double d0=0.0,d1=0.0,d2s=0.0,d3=0.0;
    #pragma unroll
    for (int d4=0; d4<16; d4++){
      double2 va = c2[d4*2], vb = c2[d4*2+1];
      d0 += qv[d4*4+0]*va.x; d1 += qv[d4*4+1]*va.y;
      d2s+= qv[d4*4+2]*vb.x; d3 += qv[d4*4+3]*vb.y;
    }
    const double dot = (d0+d1)+(d2s+d3);
    const double dist = (qn - 2.0*dot) + XN[b*NPTS + m];
    if (dist < td[10]){
      td[10] = dist; ti[10] = m;
      #pragma unroll
      for (int p=10;p>0;p--){
        if (td[p] < td[p-1]){
          double tf=td[p]; td[p]=td[p-1]; td[p-1]=tf;
          int    tt=ti[p]; ti[p]=ti[p-1]; ti[p-1]=tt;
        }
      }
    }
  }
  const size_t base = ((size_t)q*8 + part)*11;
  #pragma unroll
  for (int r=0;r<11;r++){ topd[base+r] = td[r]; topi[base+r] = ti[r]; }
}

// Merge 8x11 stable candidate lists -> top-11, drop rank 0 (self)
__global__ __launch_bounds__(256) void knn_merge_kernel(
    const double* __restrict__ topd, const int* __restrict__ topi, int* __restrict__ idxout)
{
  const int q = blockIdx.x*256 + threadIdx.x;
  double td[11]; int ti[11];
  #pragma unroll
  for (int r=0;r<11;r++){ td[r] = 1.0e308; ti[r] = 0x7fffffff; }
  const size_t base = (size_t)q*88;
  for (int s=0; s<88; s++){
    const double d = topd[base+s];
    const int  im = topi[base+s];
    if (d < td[10] || (d == td[10] && im < ti[10])){
      td[10] = d; ti[10] = im;
      #pragma unroll
      for (int p=10;p>0;p--){
        const bool sw = (td[p] < td[p-1]) || (td[p] == td[p-1] && ti[p] < ti[p-1]);
        if (sw){
          double tf=td[p]; td[p]=td[p-1]; td[p-1]=tf;
          int    tt=ti[p]; ti[p]=ti[p-1]; ti[p-1]=tt;
        }
      }
    }
  }
  #pragma unroll
  for (int j=0;j<KNB;j++) idxout[(size_t)q*KNB + j] = ti[j+1];
}

// ---------------------------------------------------------------------------
// Edge block 1 (C=3, MID=32, CH=64), precision-matched to the np reference:
// pre-BN convs in f32 (sequential, no FMA); everything post-BN in f64.
// Output x1_pre in f64. 1 wave = 1 point, 8 waves/block.
// ---------------------------------------------------------------------------
__global__ __launch_bounds__(512) void edge1_f64(
    const float* __restrict__ Xn, const int* __restrict__ idx,
    const float* __restrict__ wc1, const float* __restrict__ wcb1,
    const float* __restrict__ bn1g, const float* __restrict__ bn1b,
    const float* __restrict__ wc2, const float* __restrict__ wcb2,
    const float* __restrict__ bn2g, const float* __restrict__ bn2b,
    const float* __restrict__ xc,  const float* __restrict__ xcb,
    const float* __restrict__ xbng, const float* __restrict__ xbnb,
    const float* __restrict__ oWT, const float* __restrict__ ob,
    double* __restrict__ outX)
{
  __shared__ float wc1s[32][3];
  __shared__ float wc2s[64][33];
  __shared__ float xcs[64][7];
  __shared__ float wcb1s[32], wcb2s[64], xcbs[64];
  __shared__ double fs1d[32], fb1d[32], fs2d[64], fb2d[64], fsxd[64], fbxd[64];
  __shared__ float cenb[8][3], difb[8][3];
  __shared__ double w1bd[8][32];
  __shared__ float smw2[4096];
  __shared__ double hwbd[8][64];

  const int t = threadIdx.x;
  const double sq = sqrt(1.0 + 1e-5);
  for (int i=t; i<96;   i+=512) wc1s[i/3][i%3] = wc1[i];
  for (int i=t; i<2048; i+=512) wc2s[i/32][i%32] = wc2[i];
  for (int i=t; i<384;  i+=512) xcs[i/6][i%6] = xc[i];
  if (t < 32){ wcb1s[t]=wcb1[t]; fs1d[t]=(double)bn1g[t]/sq; fb1d[t]=(double)bn1b[t]; }
  else if (t < 96){ int o=t-32; wcb2s[o]=wcb2[o]; fs2d[o]=(double)bn2g[o]/sq; fb2d[o]=(double)bn2b[o]; }
  else if (t < 160){ int o=t-96; xcbs[o]=xcb[o]; fsxd[o]=(double)xbng[o]/sq; fbxd[o]=(double)xbnb[o]; }
  __syncthreads();

  const int wid = t>>6, lane = t&63;
  const int p = blockIdx.x*8 + wid;
  const int b = p >> 11, n = p & (NPTS-1);
  const float* xb = Xn + (size_t)b*NPTS*3;
  if (lane < 3) cenb[wid][lane] = xb[(size_t)n*3 + lane];
  __builtin_amdgcn_wave_barrier();
  const int* ip = idx + ((size_t)b*NPTS + n)*KNB;

  double w2r[KNB], hr[KNB];
  #pragma unroll
  for (int j=0;j<KNB;j++){
    const int id = ip[j];
    if (lane < 3) difb[wid][lane] = __fadd_rn(xb[(size_t)id*3 + lane], -cenb[wid][lane]);
    __builtin_amdgcn_wave_barrier();
    if (lane < 32){
      // f32 conv (np-exact): sequential c, no FMA, + bias f32
      float s = __fmul_rn(wc1s[lane][0], difb[wid][0]);
      s = __fadd_rn(s, __fmul_rn(wc1s[lane][1], difb[wid][1]));
      s = __fadd_rn(s, __fmul_rn(wc1s[lane][2], difb[wid][2]));
      s = __fadd_rn(s, wcb1s[lane]);
      // f64 bn + lrelu
      const double y = (double)s * fs1d[lane] + fb1d[lane];
      w1bd[wid][lane] = lrelu_d(y, 0.01);
    }
    __builtin_amdgcn_wave_barrier();
    {
      const int o = lane;
      // conv2: f64 accumulate (input is f64 in np), weights f32
      double s2 = 0.0;
      #pragma unroll 8
      for (int m=0;m<32;m++) s2 += (double)wc2s[o][m] * w1bd[wid][m];
      s2 += (double)wcb2s[o];
      w2r[j] = lrelu_d(s2*fs2d[o] + fb2d[o], 0.01);
      // h conv: f32 (np-exact), channels [cen0..2, dif0..2] ascending
      float s3 = __fmul_rn(xcs[o][0], cenb[wid][0]);
      s3 = __fadd_rn(s3, __fmul_rn(xcs[o][1], cenb[wid][1]));
      s3 = __fadd_rn(s3, __fmul_rn(xcs[o][2], cenb[wid][2]));
      s3 = __fadd_rn(s3, __fmul_rn(xcs[o][3], difb[wid][0]));
      s3 = __fadd_rn(s3, __fmul_rn(xcs[o][4], difb[wid][1]));
      s3 = __fadd_rn(s3, __fmul_rn(xcs[o][5], difb[wid][2]));
      s3 = __fadd_rn(s3, xcbs[o]);
      hr[j] = lrelu_d((double)s3*fsxd[o] + fbxd[o], 0.01);
    }
    __builtin_amdgcn_wave_barrier();
  }

  // f64 softmax over j, hw = h * softmax(w)
  double hw[KNB];
  {
    double mx = w2r[0];
    #pragma unroll
    for (int j=1;j<KNB;j++) mx = fmax(mx, w2r[j]);
    double ssum = 0.0;
    #pragma unroll
    for (int j=0;j<KNB;j++){ const double e = exp(w2r[j]-mx); w2r[j]=e; ssum+=e; }
    #pragma unroll
    for (int j=0;j<KNB;j++) hw[j] = hr[j]*(w2r[j]/ssum);
  }

  // phase 2: out[o] = sum_j sum_c hw[c][j]*oW[o][c][j]; oWT layout (j,c,o), f64 acc
  double acc = 0.0;
  #pragma unroll
  for (int j=0;j<KNB;j++){
    __syncthreads();
    for (int i=t; i<4096; i+=512) smw2[i] = oWT[(size_t)j*4096 + i];
    hwbd[wid][lane] = hw[j];
    __syncthreads();
    double s = 0.0;
    #pragma unroll 8
    for (int c=0;c<64;c++) s += (double)smw2[c*64 + lane]*hwbd[wid][c];
    acc += s;
  }
  outX[((size_t)b*64+lane)*NPTS + n] = acc + (double)ob[lane];
}

// ---------------------------------------------------------------------------
// AdaIN-1 in f64 (in-place on f64 x1_pre); g,be come from f32 conv output S.
// ---------------------------------------------------------------------------
__global__ __launch_bounds__(256) void adain1_f64(
    double* __restrict__ X, const float* __restrict__ S)
{
  const int c = blockIdx.x, b = blockIdx.y;
  const int t = threadIdx.x;
  const size_t base = ((size_t)b*64 + c)*NPTS;
  __shared__ double red[256];
  double v[8];
  double s = 0.0;
  #pragma unroll
  for (int i=0;i<8;i++){
    double xv = X[base + t + i*256];
    xv = lrelu_d(xv, 0.2);
    v[i] = xv; s += xv;
  }
  red[t] = s; __syncthreads();
  for (int st=128; st>0; st>>=1){ if (t<st) red[t] += red[t+st]; __syncthreads(); }
  const double mean = red[0]/(double)NPTS;
  __syncthreads();
  double s2 = 0.0;
  #pragma unroll
  for (int i=0;i<8;i++){ const double d = v[i]-mean; s2 += d*d; }
  red[t] = s2; __syncthreads();
  for (int st=128; st>0; st>>=1){ if (t<st) red[t] += red[t+st]; __syncthreads(); }
  const double var  = red[0]/(double)NPTS;
  const double rstd = 1.0/sqrt(var + 1e-5);
  const float* g  = S + ((size_t)b*128 + c)*NPTS;
  const float* be = S + ((size_t)b*128 + 64 + c)*NPTS;
  #pragma unroll
  for (int i=0;i<8;i++){
    const int n = t + i*256;
    X[base+n] = (double)g[n]*((v[i]-mean)*rstd) + (double)be[n];
  }
}

// (B,64,N) f64 channel-major -> (B,N,64) f64 + f32 n-major copies
__global__ __launch_bounds__(256) void transpose_cast64(
    const double* __restrict__ in, double* __restrict__ outT, float* __restrict__ outTf)
{
  __shared__ double tile[64][65];
  const int b = blockIdx.y, n0 = blockIdx.x*64;
  const int t = threadIdx.x;
  for (int i=t; i<4096; i+=256){ const int n=i&63, c=i>>6; tile[c][n] = in[((size_t)b*64+c)*NPTS + n0+n]; }
  __syncthreads();
  for (int i=t; i<4096; i+=256){
    const int c=i&63, n=i>>6;
    const double v = tile[c][n];
    outT [((size_t)b*NPTS+n0+n)*64 + c] = v;
    outTf[((size_t)b*NPTS+n0+n)*64 + c] = (float)v;
  }
}

// ---------------------------------------------------------------------------
// Fused edge block (fast f32): block 2 (C=64, MID=64, CH=128).
// ---------------------------------------------------------------------------
template<int C, int MID, int CH>
__global__ __launch_bounds__(512) void edge_block_kernel(
    const float* __restrict__ Xn, const int* __restrict__ idx,
    const float* __restrict__ wc1, const float* __restrict__ wcb1,
    const float* __restrict__ bn1g, const float* __restrict__ bn1b,
    const float* __restrict__ wc2, const float* __restrict__ wcb2,
    const float* __restrict__ bn2g, const float* __restrict__ bn2b,
    const float* __restrict__ xc,  const float* __restrict__ xcb,
    const float* __restrict__ xbng, const float* __restrict__ xbnb,
    const float* __restrict__ oWT, const float* __restrict__ ob,
    float* __restrict__ outX)
{
  constexpr int S1 = (C   % 2 == 0) ? C   + 1 : C   + 2;
  constexpr int S2 = (MID % 2 == 0) ? MID + 1 : MID + 2;
  constexpr int SX = 2*C + 1;
  constexpr int OFF2 = MID*S1;
  constexpr int OFFX = OFF2 + CH*S2;
  constexpr int WEND = OFFX + CH*SX;
  constexpr int WREGION = (WEND > CH*CH) ? WEND : CH*CH;
  constexpr int U = CH/64;
  __shared__ float smw[WREGION];
  __shared__ float fs1[MID], fb1[MID], fs2[CH], fb2[CH], fsx[CH], fbx[CH];
  __shared__ float cenb[8][C], difb[8][C], w1b[8][MID], hwb[8][CH];

  const int t = threadIdx.x;
  const float rs = 1.f / sqrtf(1.f + 1e-5f);
  for (int i=t; i<MID*C;  i+=512) smw[(i/C)*S1 + (i%C)] = wc1[i];
  for (int i=t; i<CH*MID; i+=512) smw[OFF2 + (i/MID)*S2 + (i%MID)] = wc2[i];
  for (int i=t; i<CH*2*C; i+=512) smw[OFFX + (i/(2*C))*SX + (i%(2*C))] = xc[i];
  if (t < MID){           float s = bn1g[t]*rs; fs1[t]=s; fb1[t]=wcb1[t]*s + bn1b[t]; }
  else if (t < MID+CH){   int o=t-MID;    float s=bn2g[o]*rs; fs2[o]=s; fb2[o]=wcb2[o]*s + bn2b[o]; }
  else if (t < MID+2*CH){ int o=t-MID-CH; float s=xbng[o]*rs; fsx[o]=s; fbx[o]=xcb[o]*s + xbnb[o]; }
  __syncthreads();

  const int wid = t>>6, lane = t&63;
  const int p = blockIdx.x*8 + wid;
  const int b = p >> 11, n = p & (NPTS-1);
  const float* xb = Xn + (size_t)b*NPTS*C;
  if (lane < C) cenb[wid][lane] = xb[(size_t)n*C + lane];
  __builtin_amdgcn_wave_barrier();
  const int* ip = idx + ((size_t)b*NPTS + n)*KNB;

  float w2r[U][KNB], hr[U][KNB];
  #pragma unroll
  for (int j=0;j<KNB;j++){
    const int id = ip[j];
    if (lane < C) difb[wid][lane] = xb[(size_t)id*C + lane] - cenb[wid][lane];
    __builtin_amdgcn_wave_barrier();
    if (lane < MID){
      const float* wr = &smw[lane*S1];
      float s = 0.f;
      #pragma unroll 4
      for (int c=0;c<C;c++) s += wr[c]*difb[wid][c];
      const float y = s*fs1[lane] + fb1[lane];
      w1b[wid][lane] = lrelu(y, 0.01f);
    }
    __builtin_amdgcn_wave_barrier();
    #pragma unroll
    for (int u=0;u<U;u++){
      const int o = lane + u*64;
      const float* wr2 = &smw[OFF2 + o*S2];
      float s = 0.f;
      #pragma unroll 4
      for (int m=0;m<MID;m++) s += wr2[m]*w1b[wid][m];
      w2r[u][j] = lrelu(s*fs2[o] + fb2[o], 0.01f);
      const float* xr = &smw[OFFX + o*SX];
      float s2 = 0.f;
      #pragma unroll 4
      for (int c=0;c<C;c++) s2 += xr[c]*cenb[wid][c];
      #pragma unroll 4
      for (int c=0;c<C;c++) s2 += xr[C+c]*difb[wid][c];
      hr[u][j] = lrelu(s2*fsx[o] + fbx[o], 0.01f);
    }
    __builtin_amdgcn_wave_barrier();
  }

  float hw[U][KNB];
  #pragma unroll
  for (int u=0;u<U;u++){
    float mx = -3.4e38f;
    #pragma unroll
    for (int j=0;j<KNB;j++) mx = fmaxf(mx, w2r[u][j]);
    float ssum = 0.f;
    #pragma unroll
    for (int j=0;j<KNB;j++){ const float e = expf(w2r[u][j]-mx); w2r[u][j]=e; ssum+=e; }
    const float inv = 1.f/ssum;
    #pragma unroll
    for (int j=0;j<KNB;j++) hw[u][j] = hr[u][j]*(w2r[u][j]*inv);
  }

  float acc[U];
  #pragma unroll
  for (int u=0;u<U;u++) acc[u] = 0.f;
  #pragma unroll
  for (int j=0;j<KNB;j++){
    __syncthreads();
    for (int i=t; i<CH*CH; i+=512) smw[i] = oWT[(size_t)j*CH*CH + i];
    #pragma unroll
    for (int u=0;u<U;u++) hwb[wid][lane+u*64] = hw[u][j];
    __syncthreads();
    #pragma unroll
    for (int u=0;u<U;u++){
      const int o = lane + u*64;
      float s = 0.f;
      #pragma unroll 4
      for (int c=0;c<CH;c++) s += smw[c*CH + o]*hwb[wid][c];
      acc[u] += s;
    }
  }
  #pragma unroll
  for (int u=0;u<U;u++){
    const int o = lane + u*64;
    outX[((size_t)b*CH+o)*NPTS + n] = acc[u] + ob[o];
  }
}

// oW (O,C,K) -> oWT (K,C,O)
template<int CH>
__global__ void owt_kernel(const float* __restrict__ oW, float* __restrict__ oWT)
{
  const int i = blockIdx.x*256 + threadIdx.x;
  if (i < CH*CH*KNB){
    const int j  = i % KNB;
    const int c2 = (i / KNB) % CH;
    const int o  = i / (KNB*CH);
    oWT[((size_t)j*CH + c2)*CH + o] = oW[i];
  }
}

// ---------------------------------------------------------------------------
// AdaIN (fast f32) for block 2
// ---------------------------------------------------------------------------
template<int CH>
__global__ __launch_bounds__(256) void adain_kernel(
    float* __restrict__ X, const float* __restrict__ S)
{
  const int c = blockIdx.x, b = blockIdx.y;
  const int t = threadIdx.x;
  const size_t base = ((size_t)b*CH + c)*NPTS;
  __shared__ float red[256];
  float v[8];
  float s = 0.f;
  #pragma unroll
  for (int i=0;i<8;i++){
    float xv = X[base + t + i*256];
    xv = lrelu(xv, 0.2f);
    v[i] = xv; s += xv;
  }
  red[t] = s; __syncthreads();
  for (int st=128; st>0; st>>=1){ if (t<st) red[t] += red[t+st]; __syncthreads(); }
  const float mean = red[0]*(1.f/NPTS);
  __syncthreads();
  float s2 = 0.f;
  #pragma unroll
  for (int i=0;i<8;i++){ const float d = v[i]-mean; s2 += d*d; }
  red[t] = s2; __syncthreads();
  for (int st=128; st>0; st>>=1){ if (t<st) red[t] += red[t+st]; __syncthreads(); }
  const float var  = red[0]*(1.f/NPTS);
  const float rstd = 1.f/sqrtf(var + 1e-5f);
  const float* g  = S + ((size_t)b*2*CH + c)*NPTS;
  const float* be = S + ((size_t)b*2*CH + CH + c)*NPTS;
  #pragma unroll
  for (int i=0;i<8;i++){
    const int n = t + i*256;
    X[base+n] = g[n]*((v[i]-mean)*rstd) + be[n];
  }
}

// fg = max over n of X2 (B,128,N)
__global__ __launch_bounds__(256) void maxn_kernel(const float* __restrict__ X, float* __restrict__ FG)
{
  const int c = blockIdx.x, b = blockIdx.y;
  const int t = threadIdx.x;
  const float* p = X + ((size_t)b*128 + c)*NPTS;
  __shared__ float red[256];
  float m = -3.4e38f;
  for (int i=t; i<NPTS; i+=256) m = fmaxf(m, p[i]);
  red[t] = m; __syncthreads();
  for (int st=128; st>0; st>>=1){ if (t<st) red[t] = fmaxf(red[t], red[t+st]); __syncthreads(); }
  if (t == 0) FG[b*128+c] = red[0];
}

// tiny FC chain
__global__ __launch_bounds__(512) void fc_kernel(
    const float* __restrict__ FG,
    const float* __restrict__ gW1, const float* __restrict__ gb1,
    const float* __restrict__ gbn1g, const float* __restrict__ gbn1b,
    const float* __restrict__ gW2, const float* __restrict__ gb2,
    const float* __restrict__ gbn2g, const float* __restrict__ gbn2b,
    const float* __restrict__ tW1, const float* __restrict__ tb1,
    float* __restrict__ FGP)
{
  const int b = blockIdx.x, t = threadIdx.x;
  __shared__ float fg[128], h1[128], h2[512];
  const float rs = 1.f/sqrtf(1.f + 1e-5f);
  if (t < 128) fg[t] = FG[b*128+t];
  __syncthreads();
  if (t < 128){
    float s = 0.f;
    for (int c=0;c<128;c++) s += gW1[t*128+c]*fg[c];
    s += gb1[t];
    s = s*(gbn1g[t]*rs) + gbn1b[t];
    h1[t] = lrelu(s, 0.01f);
  }
  __syncthreads();
  {
    float s = 0.f;
    for (int c=0;c<128;c++) s += gW2[t*128+c]*h1[c];
    s += gb2[t];
    s = s*(gbn2g[t]*rs) + gbn2b[t];
    h2[t] = lrelu(s, 0.01f);
  }
  __syncthreads();
  if (t < 256){
    float s = tb1[t];
    for (int c=0;c<512;c++) s += tW1[(size_t)t*640 + c]*h2[c];
    FGP[b*256+t] = s;
  }
}

// final conv C=64 -> M=3, transposed output (B,N,3)
__global__ __launch_bounds__(256) void t3_kernel(
    const float* __restrict__ T2, const float* __restrict__ tW3,
    const float* __restrict__ tb3, float* __restrict__ outp)
{
  __shared__ float w[192];
  const int t = threadIdx.x;
  if (t < 192) w[t] = tW3[t];
  __syncthreads();
  const int b = blockIdx.y;
  const int n = blockIdx.x*256 + t;
  float a0 = tb3[0], a1 = tb3[1], a2 = tb3[2];
  for (int c=0;c<64;c++){
    const float v = T2[((size_t)b*64+c)*NPTS + n];
    a0 += w[c]*v; a1 += w[64+c]*v; a2 += w[128+c]*v;
  }
  float* op = outp + ((size_t)b*NPTS + n)*3;
  op[0]=a0; op[1]=a1; op[2]=a2;
}

// ---------------------------------------------------------------------------
extern "C" void kernel_launch(void* const* d_in, const int* in_sizes, int n_in,
                              void* d_out, int out_size, void* d_ws, size_t ws_size,
                              hipStream_t stream)
{
  (void)in_sizes; (void)n_in; (void)out_size; (void)ws_size;
  const float* z    = (const float*)d_in[0];
  const float* x    = (const float*)d_in[1];
  const float* hW1  = (const float*)d_in[2];
  const float* hb1  = (const float*)d_in[3];
  const float* hW2  = (const float*)d_in[4];
  const float* hb2  = (const float*)d_in[5];
  const float* e1_wc1 = (const float*)d_in[6];
  const float* e1_wcb1= (const float*)d_in[7];
  const float* e1_bn1g= (const float*)d_in[8];
  const float* e1_bn1b= (const float*)d_in[9];
  const float* e1_wc2 = (const float*)d_in[10];
  const float* e1_wcb2= (const float*)d_in[11];
  const float* e1_bn2g= (const float*)d_in[12];
  const float* e1_bn2b= (const float*)d_in[13];
  const float* e1_xc  = (const float*)d_in[14];
  const float* e1_xcb = (const float*)d_in[15];
  const float* e1_xbng= (const float*)d_in[16];
  const float* e1_xbnb= (const float*)d_in[17];
  const float* e1_oW  = (const float*)d_in[18];
  const float* e1_ob  = (const float*)d_in[19];
  const float* a1_W   = (const float*)d_in[20];
  const float* a1_b   = (const float*)d_in[21];
  const float* e2_wc1 = (const float*)d_in[22];
  const float* e2_wcb1= (const float*)d_in[23];
  const float* e2_bn1g= (const float*)d_in[24];
  const float* e2_bn1b= (const float*)d_in[25];
  const float* e2_wc2 = (const float*)d_in[26];
  const float* e2_wcb2= (const float*)d_in[27];
  const float* e2_bn2g= (const float*)d_in[28];
  const float* e2_bn2b= (const float*)d_in[29];
  const float* e2_xc  = (const float*)d_in[30];
  const float* e2_xcb = (const float*)d_in[31];
  const float* e2_xbng= (const float*)d_in[32];
  const float* e2_xbnb= (const float*)d_in[33];
  const float* e2_oW  = (const float*)d_in[34];
  const float* e2_ob  = (const float*)d_in[35];
  const float* a2_W   = (const float*)d_in[36];
  const float* a2_b   = (const float*)d_in[37];
  const float* gW1    = (const float*)d_in[38];
  const float* gb1    = (const float*)d_in[39];
  const float* gbn1g  = (const float*)d_in[40];
  const float* gbn1b  = (const float*)d_in[41];
  const float* gW2    = (const float*)d_in[42];
  const float* gb2    = (const float*)d_in[43];
  const float* gbn2g  = (const float*)d_in[44];
  const float* gbn2b  = (const float*)d_in[45];
  const float* tW1    = (const float*)d_in[46];
  const float* tb1    = (const float*)d_in[47];
  const float* tW2    = (const float*)d_in[48];
  const float* tb2    = (const float*)d_in[49];
  const float* tW3    = (const float*)d_in[50];
  const float* tb3    = (const float*)d_in[51];
  float* out = (float*)d_out;
  float* ws  = (float*)d_ws;

  // workspace layout (float units)
  size_t off = 0;
  float*  ST    = ws + off; off += (size_t)BATCH*128*NPTS;    // 2M
  float*  Sbuf  = ws + off; off += (size_t)BATCH*256*NPTS;    // 4M
  float*  X1f   = ws + off; off += (size_t)BATCH*NPTS*64;     // 1M   (B,N,64) f32
  float*  X2    = ws + off; off += (size_t)BATCH*128*NPTS;    // 2M
  float*  T1    = ws + off; off += (size_t)BATCH*256*NPTS;    // 4M
  float*  T2    = ws + off; off += (size_t)BATCH*64*NPTS;     // 0.5M
  int*    IDX   = (int*)(ws + off); off += (size_t)BATCH*NPTS*KNB;  // 160K
  float*  OW1T  = ws + off; off += (size_t)64*64*KNB;         // 40K
  float*  OW2T  = ws + off; off += (size_t)128*128*KNB;       // 160K
  float*  XN3f  = ws + off; off += (size_t)BATCH*NPTS;        // 16K
  double* XN64  = (double*)(ws + off); off += (size_t)2*BATCH*NPTS; // 16K dbl
  float*  FG    = ws + off; off += (size_t)BATCH*128;
  float*  FGP   = ws + off; off += (size_t)BATCH*256;
  off = (off + 1) & ~(size_t)1;                               // align to 8B
  double* X1_64 = (double*)(ws + off); off += (size_t)2*BATCH*64*NPTS;  // 1M dbl (B,64,N)
  double* X1T64 = (double*)(ws + off); off += (size_t)2*BATCH*NPTS*64;  // 1M dbl (B,N,64)
  // kNN scratch aliased on free regions:
  double* TOPD = (double*)T1;    // 1.44M dbl <= 2M dbl capacity of T1
  int*    TOPI = (int*)Sbuf;     // 1.44M int

  // oW transposes
  owt_kernel<64> <<<(64*64*KNB+255)/256, 256, 0, stream>>>(e1_oW, OW1T);
  owt_kernel<128><<<(128*128*KNB+255)/256, 256, 0, stream>>>(e2_oW, OW2T);

  // style head (np-exact f32): st = lrelu(hW2 x lrelu(hW1 x cat(x,z)))
  head1_exact<<<dim3(32,2,8), 256, 0, stream>>>(x, z, hW1, hb1, T1);
  conv_gemm_exact<<<dim3(32,2,8), 256, 0, stream>>>(T1, hW2, 128, 0, hb2, ST, 128, 128, 1, 0.01f);

  // edge block 1: f32 np-exact kNN, mixed-precision edge block -> f64 x1_pre
  norms3_f32<<<64, 256, 0, stream>>>(x, XN3f);
  knn_part3<<<512, 256, 0, stream>>>(x, XN3f, TOPD, TOPI);
  knn_merge_kernel<<<64, 256, 0, stream>>>(TOPD, TOPI, IDX);
  edge1_f64<<<2048, 512, 0, stream>>>(
      x, IDX, e1_wc1, e1_wcb1, e1_bn1g, e1_bn1b, e1_wc2, e1_wcb2, e1_bn2g, e1_bn2b,
      e1_xc, e1_xcb, e1_xbng, e1_xbnb, OW1T, e1_ob, X1_64);
  conv_gemm_exact<<<dim3(32,2,8), 256, 0, stream>>>(ST, a1_W, 128, 0, a1_b, Sbuf, 128, 128, 0, 0.f);
  adain1_f64<<<dim3(64,8), 256, 0, stream>>>(X1_64, Sbuf);

  // edge block 2: f64 kNN on f64 x1; fast f32 everywhere after
  transpose_cast64<<<dim3(32,8), 256, 0, stream>>>(X1_64, X1T64, X1f);
  norms64d<<<64, 256, 0, stream>>>(X1T64, XN64);
  knn_part64d<<<512, 256, 0, stream>>>(X1T64, XN64, TOPD, TOPI);
  knn_merge_kernel<<<64, 256, 0, stream>>>(TOPD, TOPI, IDX);
  edge_block_kernel<64,64,128><<<2048, 512, 0, stream>>>(
      X1f, IDX, e2_wc1, e2_wcb1, e2_bn1g, e2_bn1b, e2_wc2, e2_wcb2, e2_bn2g, e2_bn2b,
      e2_xc, e2_xcb, e2_xbng, e2_xbnb, OW2T, e2_ob, X2);
  conv_gemm<<<dim3(32,4,8), 256, 0, stream>>>(ST, a2_W, 128, 0, a2_b, nullptr, Sbuf, 128, 256, 0, 0.f);
  adain_kernel<128><<<dim3(128,8), 256, 0, stream>>>(X2, Sbuf);

  // global feature + final MLP
  maxn_kernel<<<dim3(128,8), 256, 0, stream>>>(X2, FG);
  fc_kernel<<<8, 512, 0, stream>>>(FG, gW1, gb1, gbn1g, gbn1b, gW2, gb2, gbn2g, gbn2b, tW1, tb1, FGP);
  conv_gemm<<<dim3(32,4,8), 256, 0, stream>>>(X2, tW1, 640, 512, nullptr, FGP, T1, 128, 256, 1, 0.01f);
  conv_gemm<<<dim3(32,1,8), 256, 0, stream>>>(T1, tW2, 256, 0, tb2, nullptr, T2, 256, 64, 1, 0.01f);
  t3_kernel<<<dim3(8,8), 256, 0, stream>>>(T2, tW3, tb3, out);
}